// Round 3
// baseline (5439.547 us; speedup 1.0000x reference)
//
#include <hip/hip_runtime.h>
#include <hip/hip_bf16.h>

constexpr int B = 2, S = 2048, D = 1024, H = 16, Hd = 64;
constexpr int M = B * S;   // 4096 rows

__device__ __forceinline__ float bf2f(unsigned short u) {
    return __uint_as_float(((unsigned)u) << 16);
}

// ---------------------------------------------------------------------------
// Fused QKV projection: q/k/v[b,h,s,hd] = sum_k x[b,s,k] * w[k, h*64+hd]
// grid (M/64, D/64, 3), block 256. 64x64x16 SGEMM, 4x4 micro-tile, bf16 out.
// ---------------------------------------------------------------------------
__global__ __launch_bounds__(256) void qkv_gemm_kernel(
    const float* __restrict__ x, const float* __restrict__ wq,
    const float* __restrict__ wk, const float* __restrict__ wv,
    __hip_bfloat16* __restrict__ q, __hip_bfloat16* __restrict__ k,
    __hip_bfloat16* __restrict__ v)
{
    __shared__ float As[64][17];   // [m][k], +1 pad
    __shared__ float Bs[16][65];   // [k][n], +1 pad
    const float* w          = (blockIdx.z == 0) ? wq : (blockIdx.z == 1) ? wk : wv;
    __hip_bfloat16* o       = (blockIdx.z == 0) ? q  : (blockIdx.z == 1) ? k  : v;
    const int m0 = blockIdx.x * 64, n0 = blockIdx.y * 64;
    const int t = threadIdx.x, tx = t & 15, ty = t >> 4;
    const int lm = t >> 2, lk = (t & 3) * 4;
    float acc[4][4] = {};
    for (int k0 = 0; k0 < D; k0 += 16) {
        float4 a4 = *(const float4*)(x + (size_t)(m0 + lm) * D + k0 + lk);
        As[lm][lk + 0] = a4.x; As[lm][lk + 1] = a4.y;
        As[lm][lk + 2] = a4.z; As[lm][lk + 3] = a4.w;
        #pragma unroll
        for (int it = 0; it < 4; ++it) {
            int li = t + 256 * it;
            int kk = li >> 6, nn = li & 63;
            Bs[kk][nn] = w[(size_t)(k0 + kk) * D + n0 + nn];
        }
        __syncthreads();
        #pragma unroll
        for (int kk = 0; kk < 16; ++kk) {
            float a[4], b[4];
            #pragma unroll
            for (int r = 0; r < 4; ++r) a[r] = As[ty * 4 + r][kk];
            #pragma unroll
            for (int c = 0; c < 4; ++c) b[c] = Bs[kk][tx * 4 + c];
            #pragma unroll
            for (int r = 0; r < 4; ++r)
                #pragma unroll
                for (int c = 0; c < 4; ++c)
                    acc[r][c] = fmaf(a[r], b[c], acc[r][c]);
        }
        __syncthreads();
    }
    #pragma unroll
    for (int r = 0; r < 4; ++r) {
        int m = m0 + ty * 4 + r;
        int bb = m >> 11, ss = m & (S - 1);
        #pragma unroll
        for (int c = 0; c < 4; ++c) {
            int n = n0 + tx * 4 + c;
            int hh = n >> 6, hd = n & (Hd - 1);
            o[((size_t)(bb * H + hh) * S + ss) * Hd + hd] = __float2bfloat16(acc[r][c]);
        }
    }
}

// ---------------------------------------------------------------------------
// Naive-but-robust causal attention: one thread per (b, h, q_row).
// Keys looped j = 0..qrow (causality by loop bound — no -inf edge cases).
// Online softmax in registers; K/V loads vectorized as ushort4.
// ---------------------------------------------------------------------------
__global__ void attn_naive_kernel(
    const unsigned short* __restrict__ q, const unsigned short* __restrict__ k,
    const unsigned short* __restrict__ v, __hip_bfloat16* __restrict__ ctx)
{
    const int gid = blockIdx.x * 256 + threadIdx.x;   // 0 .. B*H*S-1
    const int qrow = gid & (S - 1);
    const int bh = gid >> 11;                          // b*H + h
    const size_t base = (size_t)bh * S * Hd;

    float qv[Hd];
    #pragma unroll
    for (int d4 = 0; d4 < Hd / 4; ++d4) {
        ushort4 u = *(const ushort4*)(q + base + (size_t)qrow * Hd + d4 * 4);
        qv[d4 * 4 + 0] = bf2f(u.x); qv[d4 * 4 + 1] = bf2f(u.y);
        qv[d4 * 4 + 2] = bf2f(u.z); qv[d4 * 4 + 3] = bf2f(u.w);
    }

    float m = -INFINITY, l = 0.f;
    float O[Hd];
    #pragma unroll
    for (int d = 0; d < Hd; ++d) O[d] = 0.f;

    for (int j = 0; j <= qrow; ++j) {
        const ushort4* krow = (const ushort4*)(k + base + (size_t)j * Hd);
        float s = 0.f;
        #pragma unroll
        for (int d4 = 0; d4 < Hd / 4; ++d4) {
            ushort4 u = krow[d4];
            s = fmaf(qv[d4 * 4 + 0], bf2f(u.x), s);
            s = fmaf(qv[d4 * 4 + 1], bf2f(u.y), s);
            s = fmaf(qv[d4 * 4 + 2], bf2f(u.z), s);
            s = fmaf(qv[d4 * 4 + 3], bf2f(u.w), s);
        }
        s *= 0.125f;                      // 1/sqrt(64)
        float mnew = fmaxf(m, s);
        float p  = __expf(s - mnew);
        float sf = __expf(m - mnew);      // 0 on first iteration (m = -inf)
        l = l * sf + p;
        const ushort4* vrow = (const ushort4*)(v + base + (size_t)j * Hd);
        #pragma unroll
        for (int d4 = 0; d4 < Hd / 4; ++d4) {
            ushort4 u = vrow[d4];
            O[d4 * 4 + 0] = fmaf(p, bf2f(u.x), O[d4 * 4 + 0] * sf);
            O[d4 * 4 + 1] = fmaf(p, bf2f(u.y), O[d4 * 4 + 1] * sf);
            O[d4 * 4 + 2] = fmaf(p, bf2f(u.z), O[d4 * 4 + 2] * sf);
            O[d4 * 4 + 3] = fmaf(p, bf2f(u.w), O[d4 * 4 + 3] * sf);
        }
        m = mnew;
    }

    const float inv = 1.f / l;
    const int bb = bh >> 4, hh = bh & (H - 1);
    __hip_bfloat16* crow = ctx + ((size_t)(bb * S + qrow)) * D + hh * Hd;
    #pragma unroll
    for (int d = 0; d < Hd; ++d)
        crow[d] = __float2bfloat16(O[d] * inv);
}

// ---------------------------------------------------------------------------
// Output projection: out = ctx @ wo + bo  (ctx bf16, fp32 accumulate, FP32 out)
// ---------------------------------------------------------------------------
__global__ __launch_bounds__(256) void out_gemm_kernel(
    const unsigned short* __restrict__ a, const float* __restrict__ w,
    const float* __restrict__ bias, float* __restrict__ out)
{
    __shared__ float As[64][17];
    __shared__ float Bs[16][65];
    const int m0 = blockIdx.x * 64, n0 = blockIdx.y * 64;
    const int t = threadIdx.x, tx = t & 15, ty = t >> 4;
    const int lm = t >> 2, lk = (t & 3) * 4;
    float acc[4][4] = {};
    for (int k0 = 0; k0 < D; k0 += 16) {
        ushort4 a4 = *(const ushort4*)(a + (size_t)(m0 + lm) * D + k0 + lk);
        As[lm][lk + 0] = bf2f(a4.x); As[lm][lk + 1] = bf2f(a4.y);
        As[lm][lk + 2] = bf2f(a4.z); As[lm][lk + 3] = bf2f(a4.w);
        #pragma unroll
        for (int it = 0; it < 4; ++it) {
            int li = t + 256 * it;
            int kk = li >> 6, nn = li & 63;
            Bs[kk][nn] = w[(size_t)(k0 + kk) * D + n0 + nn];
        }
        __syncthreads();
        #pragma unroll
        for (int kk = 0; kk < 16; ++kk) {
            float av[4], bv[4];
            #pragma unroll
            for (int r = 0; r < 4; ++r) av[r] = As[ty * 4 + r][kk];
            #pragma unroll
            for (int c = 0; c < 4; ++c) bv[c] = Bs[kk][tx * 4 + c];
            #pragma unroll
            for (int r = 0; r < 4; ++r)
                #pragma unroll
                for (int c = 0; c < 4; ++c)
                    acc[r][c] = fmaf(av[r], bv[c], acc[r][c]);
        }
        __syncthreads();
    }
    #pragma unroll
    for (int r = 0; r < 4; ++r) {
        size_t m = m0 + ty * 4 + r;
        #pragma unroll
        for (int c = 0; c < 4; ++c) {
            int n = n0 + tx * 4 + c;
            out[m * D + n] = acc[r][c] + bias[n];
        }
    }
}

extern "C" void kernel_launch(void* const* d_in, const int* in_sizes, int n_in,
                              void* d_out, int out_size, void* d_ws, size_t ws_size,
                              hipStream_t stream) {
    const float* x  = (const float*)d_in[0];
    const float* wq = (const float*)d_in[1];
    const float* wk = (const float*)d_in[2];
    const float* wv = (const float*)d_in[3];
    const float* wo = (const float*)d_in[4];
    const float* bo = (const float*)d_in[5];
    float* out = (float*)d_out;   // reference output dtype is float32

    // workspace (bf16): q, k, v [B,H,S,Hd] + ctx [B,S,D] -> 4 x 8 MiB = 32 MiB
    __hip_bfloat16* q   = (__hip_bfloat16*)d_ws;
    __hip_bfloat16* kk  = q  + (size_t)M * D;
    __hip_bfloat16* vv  = kk + (size_t)M * D;
    __hip_bfloat16* ctx = vv + (size_t)M * D;

    dim3 gproj(M / 64, D / 64, 3);
    qkv_gemm_kernel<<<gproj, 256, 0, stream>>>(x, wq, wk, wv, q, kk, vv);

    attn_naive_kernel<<<(B * H * S) / 256, 256, 0, stream>>>(
        (const unsigned short*)q, (const unsigned short*)kk,
        (const unsigned short*)vv, ctx);

    dim3 gout(M / 64, D / 64);
    out_gemm_kernel<<<gout, 256, 0, stream>>>((const unsigned short*)ctx, wo, bo, out);
}

// Round 4
// 951.085 us; speedup vs baseline: 5.7193x; 5.7193x over previous
//
#include <hip/hip_runtime.h>
#include <hip/hip_bf16.h>

constexpr int B = 2, S = 2048, D = 1024, H = 16, Hd = 64;
constexpr int M = B * S;   // 4096 rows

typedef __attribute__((ext_vector_type(8))) short short8;
typedef __attribute__((ext_vector_type(4))) float f32x4;

__device__ __forceinline__ float bf2f(unsigned short u) {
    return __uint_as_float(((unsigned)u) << 16);
}
__device__ __forceinline__ unsigned short f2bf(float f) {   // RNE
    unsigned u = __float_as_uint(f);
    u += 0x7FFF + ((u >> 16) & 1);
    return (unsigned short)(u >> 16);
}

// ---------------------------------------------------------------------------
// Fused QKV projection. q,k -> [B,H,S,Hd] bf16; v -> TRANSPOSED [B,H,Hd,S]
// so PV's MFMA B-fragments are contiguous along kc.
// ---------------------------------------------------------------------------
__global__ __launch_bounds__(256) void qkv_gemm_kernel(
    const float* __restrict__ x, const float* __restrict__ wq,
    const float* __restrict__ wk, const float* __restrict__ wv,
    __hip_bfloat16* __restrict__ q, __hip_bfloat16* __restrict__ k,
    __hip_bfloat16* __restrict__ vt)
{
    __shared__ float As[64][17];
    __shared__ float Bs[16][65];
    const int z = blockIdx.z;
    const float* w          = (z == 0) ? wq : (z == 1) ? wk : wv;
    __hip_bfloat16* o       = (z == 0) ? q  : (z == 1) ? k  : vt;
    const int m0 = blockIdx.x * 64, n0 = blockIdx.y * 64;
    const int t = threadIdx.x, tx = t & 15, ty = t >> 4;
    const int lm = t >> 2, lk = (t & 3) * 4;
    float acc[4][4] = {};
    for (int k0 = 0; k0 < D; k0 += 16) {
        float4 a4 = *(const float4*)(x + (size_t)(m0 + lm) * D + k0 + lk);
        As[lm][lk + 0] = a4.x; As[lm][lk + 1] = a4.y;
        As[lm][lk + 2] = a4.z; As[lm][lk + 3] = a4.w;
        #pragma unroll
        for (int it = 0; it < 4; ++it) {
            int li = t + 256 * it;
            int kk = li >> 6, nn = li & 63;
            Bs[kk][nn] = w[(size_t)(k0 + kk) * D + n0 + nn];
        }
        __syncthreads();
        #pragma unroll
        for (int kk = 0; kk < 16; ++kk) {
            float a[4], b[4];
            #pragma unroll
            for (int r = 0; r < 4; ++r) a[r] = As[ty * 4 + r][kk];
            #pragma unroll
            for (int c = 0; c < 4; ++c) b[c] = Bs[kk][tx * 4 + c];
            #pragma unroll
            for (int r = 0; r < 4; ++r)
                #pragma unroll
                for (int c = 0; c < 4; ++c)
                    acc[r][c] = fmaf(a[r], b[c], acc[r][c]);
        }
        __syncthreads();
    }
    #pragma unroll
    for (int r = 0; r < 4; ++r) {
        int m = m0 + ty * 4 + r;
        int bb = m >> 11, ss = m & (S - 1);
        #pragma unroll
        for (int c = 0; c < 4; ++c) {
            int n = n0 + tx * 4 + c;
            int hh = n >> 6, hd = n & (Hd - 1);
            __hip_bfloat16 val = __float2bfloat16(acc[r][c]);
            if (z == 2)   // V transposed: [B,H,Hd,S]
                o[((size_t)(bb * H + hh) * Hd + hd) * S + ss] = val;
            else          // Q,K: [B,H,S,Hd]
                o[((size_t)(bb * H + hh) * S + ss) * Hd + hd] = val;
        }
    }
}

// ---------------------------------------------------------------------------
// MFMA causal flash attention. Block = 4 independent waves; wave owns a
// 16-row Q strip. 64-key tiles; mfma_f32_16x16x32_bf16.
// A-frag: row = lane&15, k = (lane>>4)*8 + i (contiguous).
// C/D:    col = lane&15, row = (lane>>4)*4 + reg.
// ---------------------------------------------------------------------------
__global__ __launch_bounds__(256) void attn_mfma_kernel(
    const unsigned short* __restrict__ q, const unsigned short* __restrict__ k,
    const unsigned short* __restrict__ vt, __hip_bfloat16* __restrict__ ctx)
{
    __shared__ unsigned short P_lds[4][16][72];   // per-wave P strip, 144B rows
    const int w = threadIdx.x >> 6, l = threadIdx.x & 63;
    const int lr = l & 15, lg = l >> 4;
    const int hh = blockIdx.y, bb = blockIdx.z;
    const int q0 = blockIdx.x * 64 + w * 16;
    const size_t base  = (size_t)(bb * H + hh) * S * Hd;   // q,k
    const size_t vbase = (size_t)(bb * H + hh) * Hd * S;   // vt

    short8 qf[2];
    #pragma unroll
    for (int c = 0; c < 2; ++c)
        qf[c] = *(const short8*)(q + base + (size_t)(q0 + lr) * Hd + c * 32 + lg * 8);

    f32x4 accO[4];
    #pragma unroll
    for (int hb = 0; hb < 4; ++hb) accO[hb] = (f32x4){0.f, 0.f, 0.f, 0.f};
    float mrow[4], lrow[4];
    #pragma unroll
    for (int r = 0; r < 4; ++r) { mrow[r] = -INFINITY; lrow[r] = 0.f; }

    const int diag = q0 >> 6;
    for (int kt = 0; kt <= diag; ++kt) {
        // ---- S = Q K^T (16 x 64 strip) ----
        f32x4 accS[4];
        #pragma unroll
        for (int kc = 0; kc < 4; ++kc) {
            accS[kc] = (f32x4){0.f, 0.f, 0.f, 0.f};
            #pragma unroll
            for (int c = 0; c < 2; ++c) {
                short8 kf = *(const short8*)(k + base +
                    (size_t)(kt * 64 + kc * 16 + lr) * Hd + c * 32 + lg * 8);
                accS[kc] = __builtin_amdgcn_mfma_f32_16x16x32_bf16(qf[c], kf, accS[kc], 0, 0, 0);
            }
        }

        // ---- online softmax on the 16x64 strip ----
        float ps[4][4];
        #pragma unroll
        for (int kc = 0; kc < 4; ++kc)
            #pragma unroll
            for (int r = 0; r < 4; ++r) {
                float s = accS[kc][r] * 0.125f;
                if (kt == diag) {
                    int kj = kt * 64 + kc * 16 + lr;
                    int qi = q0 + lg * 4 + r;
                    if (kj > qi) s = -INFINITY;
                }
                ps[kc][r] = s;
            }
        float sf[4];
        #pragma unroll
        for (int r = 0; r < 4; ++r) {
            float tm = fmaxf(fmaxf(ps[0][r], ps[1][r]), fmaxf(ps[2][r], ps[3][r]));
            #pragma unroll
            for (int msk = 1; msk < 16; msk <<= 1)
                tm = fmaxf(tm, __shfl_xor(tm, msk));
            float mn = fmaxf(mrow[r], tm);
            float rs = 0.f;
            #pragma unroll
            for (int kc = 0; kc < 4; ++kc) {
                float p = __expf(ps[kc][r] - mn);
                ps[kc][r] = p;
                rs += p;
            }
            #pragma unroll
            for (int msk = 1; msk < 16; msk <<= 1)
                rs += __shfl_xor(rs, msk);
            sf[r] = __expf(mrow[r] - mn);
            lrow[r] = lrow[r] * sf[r] + rs;
            mrow[r] = mn;
        }
        #pragma unroll
        for (int hb = 0; hb < 4; ++hb)
            #pragma unroll
            for (int r = 0; r < 4; ++r) accO[hb][r] *= sf[r];

        // ---- P strip -> LDS (D-layout scatter), re-read as A-frags ----
        #pragma unroll
        for (int kc = 0; kc < 4; ++kc)
            #pragma unroll
            for (int r = 0; r < 4; ++r)
                P_lds[w][lg * 4 + r][kc * 16 + lr] = f2bf(ps[kc][r]);
        short8 pa[2];
        #pragma unroll
        for (int c = 0; c < 2; ++c)
            pa[c] = *(const short8*)&P_lds[w][lr][c * 32 + lg * 8];

        // ---- O += P V ----
        #pragma unroll
        for (int hb = 0; hb < 4; ++hb) {
            #pragma unroll
            for (int c = 0; c < 2; ++c) {
                short8 vf = *(const short8*)(vt + vbase +
                    (size_t)(hb * 16 + lr) * S + kt * 64 + c * 32 + lg * 8);
                accO[hb] = __builtin_amdgcn_mfma_f32_16x16x32_bf16(pa[c], vf, accO[hb], 0, 0, 0);
            }
        }
    }

    // ---- epilogue: ctx[B,S,D] bf16 ----
    #pragma unroll
    for (int r = 0; r < 4; ++r) {
        float inv = 1.f / lrow[r];
        size_t row = (size_t)(bb * S + q0 + lg * 4 + r) * D + hh * Hd;
        #pragma unroll
        for (int hb = 0; hb < 4; ++hb)
            ctx[row + hb * 16 + lr] = __float2bfloat16(accO[hb][r] * inv);
    }
}

// ---------------------------------------------------------------------------
// Output projection: out = ctx @ wo + bo  (ctx bf16, fp32 accumulate, fp32 out)
// ---------------------------------------------------------------------------
__global__ __launch_bounds__(256) void out_gemm_kernel(
    const unsigned short* __restrict__ a, const float* __restrict__ w,
    const float* __restrict__ bias, float* __restrict__ out)
{
    __shared__ float As[64][17];
    __shared__ float Bs[16][65];
    const int m0 = blockIdx.x * 64, n0 = blockIdx.y * 64;
    const int t = threadIdx.x, tx = t & 15, ty = t >> 4;
    const int lm = t >> 2, lk = (t & 3) * 4;
    float acc[4][4] = {};
    for (int k0 = 0; k0 < D; k0 += 16) {
        ushort4 a4 = *(const ushort4*)(a + (size_t)(m0 + lm) * D + k0 + lk);
        As[lm][lk + 0] = bf2f(a4.x); As[lm][lk + 1] = bf2f(a4.y);
        As[lm][lk + 2] = bf2f(a4.z); As[lm][lk + 3] = bf2f(a4.w);
        #pragma unroll
        for (int it = 0; it < 4; ++it) {
            int li = t + 256 * it;
            int kk = li >> 6, nn = li & 63;
            Bs[kk][nn] = w[(size_t)(k0 + kk) * D + n0 + nn];
        }
        __syncthreads();
        #pragma unroll
        for (int kk = 0; kk < 16; ++kk) {
            float av[4], bv[4];
            #pragma unroll
            for (int r = 0; r < 4; ++r) av[r] = As[ty * 4 + r][kk];
            #pragma unroll
            for (int c = 0; c < 4; ++c) bv[c] = Bs[kk][tx * 4 + c];
            #pragma unroll
            for (int r = 0; r < 4; ++r)
                #pragma unroll
                for (int c = 0; c < 4; ++c)
                    acc[r][c] = fmaf(av[r], bv[c], acc[r][c]);
        }
        __syncthreads();
    }
    #pragma unroll
    for (int r = 0; r < 4; ++r) {
        size_t m = m0 + ty * 4 + r;
        #pragma unroll
        for (int c = 0; c < 4; ++c) {
            int n = n0 + tx * 4 + c;
            out[m * D + n] = acc[r][c] + bias[n];
        }
    }
}

extern "C" void kernel_launch(void* const* d_in, const int* in_sizes, int n_in,
                              void* d_out, int out_size, void* d_ws, size_t ws_size,
                              hipStream_t stream) {
    const float* x  = (const float*)d_in[0];
    const float* wq = (const float*)d_in[1];
    const float* wk = (const float*)d_in[2];
    const float* wv = (const float*)d_in[3];
    const float* wo = (const float*)d_in[4];
    const float* bo = (const float*)d_in[5];
    float* out = (float*)d_out;

    // workspace (bf16): q,k [B,H,S,Hd], vt [B,H,Hd,S], ctx [B,S,D] = 32 MiB
    __hip_bfloat16* q   = (__hip_bfloat16*)d_ws;
    __hip_bfloat16* kk  = q  + (size_t)M * D;
    __hip_bfloat16* vt  = kk + (size_t)M * D;
    __hip_bfloat16* ctx = vt + (size_t)M * D;

    dim3 gproj(M / 64, D / 64, 3);
    qkv_gemm_kernel<<<gproj, 256, 0, stream>>>(x, wq, wk, wv, q, kk, vt);

    dim3 gattn(S / 64, H, B);
    attn_mfma_kernel<<<gattn, 256, 0, stream>>>(
        (const unsigned short*)q, (const unsigned short*)kk,
        (const unsigned short*)vt, ctx);

    dim3 gout(M / 64, D / 64);
    out_gemm_kernel<<<gout, 256, 0, stream>>>((const unsigned short*)ctx, wo, bo, out);
}

// Round 5
// 366.978 us; speedup vs baseline: 14.8225x; 2.5917x over previous
//
#include <hip/hip_runtime.h>
#include <hip/hip_bf16.h>

constexpr int B = 2, S = 2048, D = 1024, H = 16, Hd = 64;
constexpr int M = B * S;   // 4096 rows
constexpr int K = 1024;

typedef __attribute__((ext_vector_type(8))) short short8;
typedef __attribute__((ext_vector_type(4))) float f32x4;

__device__ __forceinline__ float bf2f(unsigned short u) {
    return __uint_as_float(((unsigned)u) << 16);
}
__device__ __forceinline__ unsigned short f2bf(float f) {   // RNE
    unsigned u = __float_as_uint(f);
    u += 0x7FFF + ((u >> 16) & 1);
    return (unsigned short)(u >> 16);
}
__device__ __forceinline__ void gload_lds16(const unsigned short* g, unsigned short* l) {
    __builtin_amdgcn_global_load_lds(
        (const __attribute__((address_space(1))) void*)g,
        (__attribute__((address_space(3))) void*)l, 16, 0, 0);
}

// ---------------------------------------------------------------------------
// x fp32 -> bf16, 8 elems/thread
// ---------------------------------------------------------------------------
__global__ __launch_bounds__(256) void convert_x_kernel(
    const float* __restrict__ x, unsigned short* __restrict__ xb)
{
    const size_t i = ((size_t)blockIdx.x * 256 + threadIdx.x) * 8;
    float4 a = *(const float4*)(x + i), b = *(const float4*)(x + i + 4);
    ushort4 u0 = {f2bf(a.x), f2bf(a.y), f2bf(a.z), f2bf(a.w)};
    ushort4 u1 = {f2bf(b.x), f2bf(b.y), f2bf(b.z), f2bf(b.w)};
    *(ushort4*)(xb + i) = u0;
    *(ushort4*)(xb + i + 4) = u1;
}

// ---------------------------------------------------------------------------
// Weight transpose+convert: w [K,N] fp32 -> wt [N,K] bf16 (padded-LDS tile).
// z: 0,1,2 -> wq,wk,wv into wqkv_t (n-offset z*1024); 3 -> wo into wo_t.
// ---------------------------------------------------------------------------
__global__ __launch_bounds__(256) void transpose_w_kernel(
    const float* __restrict__ wq, const float* __restrict__ wk,
    const float* __restrict__ wv, const float* __restrict__ wo,
    unsigned short* __restrict__ wqkv_t, unsigned short* __restrict__ wo_t)
{
    __shared__ float tile[64][65];
    const int z = blockIdx.z;
    const float* w = (z == 0) ? wq : (z == 1) ? wk : (z == 2) ? wv : wo;
    unsigned short* dst = (z == 3) ? wo_t : wqkv_t + (size_t)z * K * K;
    const int k0 = blockIdx.x * 64, n0 = blockIdx.y * 64;
    const int t = threadIdx.x;
    #pragma unroll
    for (int it = 0; it < 16; ++it) {
        int idx = t + it * 256;
        tile[idx >> 6][idx & 63] = w[(size_t)(k0 + (idx >> 6)) * K + n0 + (idx & 63)];
    }
    __syncthreads();
    #pragma unroll
    for (int it = 0; it < 16; ++it) {
        int idx = t + it * 256;
        int r = idx >> 6, c = idx & 63;     // r = n-in-tile, c = k-in-tile
        dst[(size_t)(n0 + r) * K + k0 + c] = f2bf(tile[c][r]);
    }
}

// ---------------------------------------------------------------------------
// Fused QKV MFMA GEMM: C[m][n] = sum_k x_bf[m][k] * wqkv_t[n][k], N = 3072.
// 128x128 tile, 4 waves (2x2), BK=32, global_load_lds staging (m97 structure).
// Epilogue scatters: n>>10 selects q / k / v-transposed.
// ---------------------------------------------------------------------------
__global__ __launch_bounds__(256) void qkv_mfma_kernel(
    const unsigned short* __restrict__ xa, const unsigned short* __restrict__ bt,
    unsigned short* __restrict__ q, unsigned short* __restrict__ k,
    unsigned short* __restrict__ vt)
{
    __shared__ unsigned short A_lds[128][32];
    __shared__ unsigned short B_lds[128][32];
    const int t = threadIdx.x, w = t >> 6, l = t & 63;
    const int lr = l & 15, lg = l >> 4;
    const int wm = w >> 1, wn = w & 1;
    const int m0 = blockIdx.x * 128, n0 = blockIdx.y * 128;
    const int srow = l >> 2, skofs = (l & 3) * 8;   // staging: lane -> row/4, k-offset

    f32x4 acc[4][4];
    #pragma unroll
    for (int i = 0; i < 4; ++i)
        #pragma unroll
        for (int j = 0; j < 4; ++j) acc[i][j] = (f32x4){0.f, 0.f, 0.f, 0.f};

    for (int k0 = 0; k0 < K; k0 += 32) {
        #pragma unroll
        for (int p = 0; p < 2; ++p) {
            const int c = w * 2 + p;   // 16-row chunk
            gload_lds16(xa + (size_t)(m0 + c * 16 + srow) * K + k0 + skofs, &A_lds[c * 16][0]);
            gload_lds16(bt + (size_t)(n0 + c * 16 + srow) * K + k0 + skofs, &B_lds[c * 16][0]);
        }
        __syncthreads();
        short8 af[4], bf[4];
        #pragma unroll
        for (int i = 0; i < 4; ++i) af[i] = *(const short8*)&A_lds[wm * 64 + i * 16 + lr][lg * 8];
        #pragma unroll
        for (int j = 0; j < 4; ++j) bf[j] = *(const short8*)&B_lds[wn * 64 + j * 16 + lr][lg * 8];
        #pragma unroll
        for (int i = 0; i < 4; ++i)
            #pragma unroll
            for (int j = 0; j < 4; ++j)
                acc[i][j] = __builtin_amdgcn_mfma_f32_16x16x32_bf16(af[i], bf[j], acc[i][j], 0, 0, 0);
        __syncthreads();
    }

    const int z = (n0 >> 10);   // block-uniform: which of q/k/v
    #pragma unroll
    for (int i = 0; i < 4; ++i) {
        const int mbase = m0 + wm * 64 + i * 16 + lg * 4;
        #pragma unroll
        for (int j = 0; j < 4; ++j) {
            const int n = n0 + wn * 64 + j * 16 + lr;
            const int nn = n & 1023, hh = nn >> 6, hd = nn & 63;
            #pragma unroll
            for (int r = 0; r < 4; ++r) {
                const int mm = mbase + r, bb = mm >> 11, ss = mm & (S - 1);
                const unsigned short val = f2bf(acc[i][j][r]);
                if (z == 0)      q[((size_t)(bb * H + hh) * S + ss) * Hd + hd] = val;
                else if (z == 1) k[((size_t)(bb * H + hh) * S + ss) * Hd + hd] = val;
                else             vt[((size_t)(bb * H + hh) * Hd + hd) * S + ss] = val;
            }
        }
    }
}

// ---------------------------------------------------------------------------
// Output projection MFMA GEMM: out[m][n] = sum_k ctx[m][k]*wo_t[n][k] + bo[n]
// ---------------------------------------------------------------------------
__global__ __launch_bounds__(256) void out_mfma_kernel(
    const unsigned short* __restrict__ a, const unsigned short* __restrict__ bt,
    const float* __restrict__ bias, float* __restrict__ out)
{
    __shared__ unsigned short A_lds[128][32];
    __shared__ unsigned short B_lds[128][32];
    const int t = threadIdx.x, w = t >> 6, l = t & 63;
    const int lr = l & 15, lg = l >> 4;
    const int wm = w >> 1, wn = w & 1;
    const int m0 = blockIdx.x * 128, n0 = blockIdx.y * 128;
    const int srow = l >> 2, skofs = (l & 3) * 8;

    f32x4 acc[4][4];
    #pragma unroll
    for (int i = 0; i < 4; ++i)
        #pragma unroll
        for (int j = 0; j < 4; ++j) acc[i][j] = (f32x4){0.f, 0.f, 0.f, 0.f};

    for (int k0 = 0; k0 < K; k0 += 32) {
        #pragma unroll
        for (int p = 0; p < 2; ++p) {
            const int c = w * 2 + p;
            gload_lds16(a  + (size_t)(m0 + c * 16 + srow) * K + k0 + skofs, &A_lds[c * 16][0]);
            gload_lds16(bt + (size_t)(n0 + c * 16 + srow) * K + k0 + skofs, &B_lds[c * 16][0]);
        }
        __syncthreads();
        short8 af[4], bf[4];
        #pragma unroll
        for (int i = 0; i < 4; ++i) af[i] = *(const short8*)&A_lds[wm * 64 + i * 16 + lr][lg * 8];
        #pragma unroll
        for (int j = 0; j < 4; ++j) bf[j] = *(const short8*)&B_lds[wn * 64 + j * 16 + lr][lg * 8];
        #pragma unroll
        for (int i = 0; i < 4; ++i)
            #pragma unroll
            for (int j = 0; j < 4; ++j)
                acc[i][j] = __builtin_amdgcn_mfma_f32_16x16x32_bf16(af[i], bf[j], acc[i][j], 0, 0, 0);
        __syncthreads();
    }

    #pragma unroll
    for (int i = 0; i < 4; ++i) {
        const int mbase = m0 + wm * 64 + i * 16 + lg * 4;
        #pragma unroll
        for (int j = 0; j < 4; ++j) {
            const int n = n0 + wn * 64 + j * 16 + lr;
            const float bv = bias[n];
            #pragma unroll
            for (int r = 0; r < 4; ++r)
                out[(size_t)(mbase + r) * D + n] = acc[i][j][r] + bv;
        }
    }
}

// ---------------------------------------------------------------------------
// MFMA causal flash attention (unchanged from round 4 — passing).
// ---------------------------------------------------------------------------
__global__ __launch_bounds__(256) void attn_mfma_kernel(
    const unsigned short* __restrict__ q, const unsigned short* __restrict__ k,
    const unsigned short* __restrict__ vt, unsigned short* __restrict__ ctx)
{
    __shared__ unsigned short P_lds[4][16][72];
    const int w = threadIdx.x >> 6, l = threadIdx.x & 63;
    const int lr = l & 15, lg = l >> 4;
    const int hh = blockIdx.y, bb = blockIdx.z;
    const int q0 = blockIdx.x * 64 + w * 16;
    const size_t base  = (size_t)(bb * H + hh) * S * Hd;
    const size_t vbase = (size_t)(bb * H + hh) * Hd * S;

    short8 qf[2];
    #pragma unroll
    for (int c = 0; c < 2; ++c)
        qf[c] = *(const short8*)(q + base + (size_t)(q0 + lr) * Hd + c * 32 + lg * 8);

    f32x4 accO[4];
    #pragma unroll
    for (int hb = 0; hb < 4; ++hb) accO[hb] = (f32x4){0.f, 0.f, 0.f, 0.f};
    float mrow[4], lrow[4];
    #pragma unroll
    for (int r = 0; r < 4; ++r) { mrow[r] = -INFINITY; lrow[r] = 0.f; }

    const int diag = q0 >> 6;
    for (int kt = 0; kt <= diag; ++kt) {
        f32x4 accS[4];
        #pragma unroll
        for (int kc = 0; kc < 4; ++kc) {
            accS[kc] = (f32x4){0.f, 0.f, 0.f, 0.f};
            #pragma unroll
            for (int c = 0; c < 2; ++c) {
                short8 kf = *(const short8*)(k + base +
                    (size_t)(kt * 64 + kc * 16 + lr) * Hd + c * 32 + lg * 8);
                accS[kc] = __builtin_amdgcn_mfma_f32_16x16x32_bf16(qf[c], kf, accS[kc], 0, 0, 0);
            }
        }

        float ps[4][4];
        #pragma unroll
        for (int kc = 0; kc < 4; ++kc)
            #pragma unroll
            for (int r = 0; r < 4; ++r) {
                float s = accS[kc][r] * 0.125f;
                if (kt == diag) {
                    int kj = kt * 64 + kc * 16 + lr;
                    int qi = q0 + lg * 4 + r;
                    if (kj > qi) s = -INFINITY;
                }
                ps[kc][r] = s;
            }
        float sf[4];
        #pragma unroll
        for (int r = 0; r < 4; ++r) {
            float tm = fmaxf(fmaxf(ps[0][r], ps[1][r]), fmaxf(ps[2][r], ps[3][r]));
            #pragma unroll
            for (int msk = 1; msk < 16; msk <<= 1)
                tm = fmaxf(tm, __shfl_xor(tm, msk));
            float mn = fmaxf(mrow[r], tm);
            float rs = 0.f;
            #pragma unroll
            for (int kc = 0; kc < 4; ++kc) {
                float p = __expf(ps[kc][r] - mn);
                ps[kc][r] = p;
                rs += p;
            }
            #pragma unroll
            for (int msk = 1; msk < 16; msk <<= 1)
                rs += __shfl_xor(rs, msk);
            sf[r] = __expf(mrow[r] - mn);
            lrow[r] = lrow[r] * sf[r] + rs;
            mrow[r] = mn;
        }
        #pragma unroll
        for (int hb = 0; hb < 4; ++hb)
            #pragma unroll
            for (int r = 0; r < 4; ++r) accO[hb][r] *= sf[r];

        #pragma unroll
        for (int kc = 0; kc < 4; ++kc)
            #pragma unroll
            for (int r = 0; r < 4; ++r)
                P_lds[w][lg * 4 + r][kc * 16 + lr] = f2bf(ps[kc][r]);
        short8 pa[2];
        #pragma unroll
        for (int c = 0; c < 2; ++c)
            pa[c] = *(const short8*)&P_lds[w][lr][c * 32 + lg * 8];

        #pragma unroll
        for (int hb = 0; hb < 4; ++hb) {
            #pragma unroll
            for (int c = 0; c < 2; ++c) {
                short8 vf = *(const short8*)(vt + vbase +
                    (size_t)(hb * 16 + lr) * S + kt * 64 + c * 32 + lg * 8);
                accO[hb] = __builtin_amdgcn_mfma_f32_16x16x32_bf16(pa[c], vf, accO[hb], 0, 0, 0);
            }
        }
    }

    #pragma unroll
    for (int r = 0; r < 4; ++r) {
        float inv = 1.f / lrow[r];
        size_t row = (size_t)(bb * S + q0 + lg * 4 + r) * D + hh * Hd;
        #pragma unroll
        for (int hb = 0; hb < 4; ++hb)
            ctx[row + hb * 16 + lr] = f2bf(accO[hb][r] * inv);
    }
}

extern "C" void kernel_launch(void* const* d_in, const int* in_sizes, int n_in,
                              void* d_out, int out_size, void* d_ws, size_t ws_size,
                              hipStream_t stream) {
    const float* x  = (const float*)d_in[0];
    const float* wq = (const float*)d_in[1];
    const float* wk = (const float*)d_in[2];
    const float* wv = (const float*)d_in[3];
    const float* wo = (const float*)d_in[4];
    const float* bo = (const float*)d_in[5];
    float* out = (float*)d_out;

    // workspace layout (40 MiB):
    //  [0,8M)   x_bf  (bf16 x)            -- aliased by ctx after qkv GEMM
    //  [8,16M)  q  [B,H,S,Hd]
    //  [16,24M) k  [B,H,S,Hd]
    //  [24,32M) vt [B,H,Hd,S]
    //  [32,38M) wqkv_t [3072][1024] bf16
    //  [38,40M) wo_t   [1024][1024] bf16
    char* ws = (char*)d_ws;
    unsigned short* x_bf   = (unsigned short*)ws;
    unsigned short* q      = (unsigned short*)(ws + ((size_t)8  << 20));
    unsigned short* kk     = (unsigned short*)(ws + ((size_t)16 << 20));
    unsigned short* vt     = (unsigned short*)(ws + ((size_t)24 << 20));
    unsigned short* ctx    = x_bf;
    unsigned short* wqkv_t = (unsigned short*)(ws + ((size_t)32 << 20));
    unsigned short* wo_t   = (unsigned short*)(ws + ((size_t)38 << 20));

    convert_x_kernel<<<(M * K) / (256 * 8), 256, 0, stream>>>(x, x_bf);
    dim3 gtr(K / 64, K / 64, 4);
    transpose_w_kernel<<<gtr, 256, 0, stream>>>(wq, wk, wv, wo, wqkv_t, wo_t);

    dim3 gqkv(M / 128, 3072 / 128);
    qkv_mfma_kernel<<<gqkv, 256, 0, stream>>>(x_bf, wqkv_t, q, kk, vt);

    dim3 gattn(S / 64, H, B);
    attn_mfma_kernel<<<gattn, 256, 0, stream>>>(q, kk, vt, ctx);

    dim3 gout(M / 128, D / 128);
    out_mfma_kernel<<<gout, 256, 0, stream>>>(ctx, wo_t, bo, out);
}

// Round 6
// 145.262 us; speedup vs baseline: 37.4464x; 2.5263x over previous
//
#include <hip/hip_runtime.h>
#include <hip/hip_bf16.h>

constexpr int B = 2, S = 2048, D = 1024, H = 16, Hd = 64;
constexpr int M = B * S;   // 4096 rows
constexpr int K = 1024;

typedef __attribute__((ext_vector_type(8))) short short8;
typedef __attribute__((ext_vector_type(4))) float f32x4;

__device__ __forceinline__ float bf2f(unsigned short u) {
    return __uint_as_float(((unsigned)u) << 16);
}
__device__ __forceinline__ unsigned short f2bf(float f) {   // RNE
    unsigned u = __float_as_uint(f);
    u += 0x7FFF + ((u >> 16) & 1);
    return (unsigned short)(u >> 16);
}
__device__ __forceinline__ void gload_lds16(const unsigned short* g, unsigned short* l) {
    __builtin_amdgcn_global_load_lds(
        (const __attribute__((address_space(1))) void*)g,
        (__attribute__((address_space(3))) void*)l, 16, 0, 0);
}

// ---------------------------------------------------------------------------
// x fp32 -> bf16, 8 elems/thread
// ---------------------------------------------------------------------------
__global__ __launch_bounds__(256) void convert_x_kernel(
    const float* __restrict__ x, unsigned short* __restrict__ xb)
{
    const size_t i = ((size_t)blockIdx.x * 256 + threadIdx.x) * 8;
    float4 a = *(const float4*)(x + i), b = *(const float4*)(x + i + 4);
    ushort4 u0 = {f2bf(a.x), f2bf(a.y), f2bf(a.z), f2bf(a.w)};
    ushort4 u1 = {f2bf(b.x), f2bf(b.y), f2bf(b.z), f2bf(b.w)};
    *(ushort4*)(xb + i) = u0;
    *(ushort4*)(xb + i + 4) = u1;
}

// ---------------------------------------------------------------------------
// Weight transpose+convert: w [K,N] fp32 -> wt [N,K] bf16 (padded-LDS tile).
// ---------------------------------------------------------------------------
__global__ __launch_bounds__(256) void transpose_w_kernel(
    const float* __restrict__ wq, const float* __restrict__ wk,
    const float* __restrict__ wv, const float* __restrict__ wo,
    unsigned short* __restrict__ wqkv_t, unsigned short* __restrict__ wo_t)
{
    __shared__ float tile[64][65];
    const int z = blockIdx.z;
    const float* w = (z == 0) ? wq : (z == 1) ? wk : (z == 2) ? wv : wo;
    unsigned short* dst = (z == 3) ? wo_t : wqkv_t + (size_t)z * K * K;
    const int k0 = blockIdx.x * 64, n0 = blockIdx.y * 64;
    const int t = threadIdx.x;
    #pragma unroll
    for (int it = 0; it < 16; ++it) {
        int idx = t + it * 256;
        tile[idx >> 6][idx & 63] = w[(size_t)(k0 + (idx >> 6)) * K + n0 + (idx & 63)];
    }
    __syncthreads();
    #pragma unroll
    for (int it = 0; it < 16; ++it) {
        int idx = t + it * 256;
        int r = idx >> 6, c = idx & 63;
        dst[(size_t)(n0 + r) * K + k0 + c] = f2bf(tile[c][r]);
    }
}

// ---------------------------------------------------------------------------
// Fused QKV MFMA GEMM (m97 structure) — unchanged from round 5 (passing).
// ---------------------------------------------------------------------------
__global__ __launch_bounds__(256) void qkv_mfma_kernel(
    const unsigned short* __restrict__ xa, const unsigned short* __restrict__ bt,
    unsigned short* __restrict__ q, unsigned short* __restrict__ k,
    unsigned short* __restrict__ vt)
{
    __shared__ unsigned short A_lds[128][32];
    __shared__ unsigned short B_lds[128][32];
    const int t = threadIdx.x, w = t >> 6, l = t & 63;
    const int lr = l & 15, lg = l >> 4;
    const int wm = w >> 1, wn = w & 1;
    const int m0 = blockIdx.x * 128, n0 = blockIdx.y * 128;
    const int srow = l >> 2, skofs = (l & 3) * 8;

    f32x4 acc[4][4];
    #pragma unroll
    for (int i = 0; i < 4; ++i)
        #pragma unroll
        for (int j = 0; j < 4; ++j) acc[i][j] = (f32x4){0.f, 0.f, 0.f, 0.f};

    for (int k0 = 0; k0 < K; k0 += 32) {
        #pragma unroll
        for (int p = 0; p < 2; ++p) {
            const int c = w * 2 + p;
            gload_lds16(xa + (size_t)(m0 + c * 16 + srow) * K + k0 + skofs, &A_lds[c * 16][0]);
            gload_lds16(bt + (size_t)(n0 + c * 16 + srow) * K + k0 + skofs, &B_lds[c * 16][0]);
        }
        __syncthreads();
        short8 af[4], bf[4];
        #pragma unroll
        for (int i = 0; i < 4; ++i) af[i] = *(const short8*)&A_lds[wm * 64 + i * 16 + lr][lg * 8];
        #pragma unroll
        for (int j = 0; j < 4; ++j) bf[j] = *(const short8*)&B_lds[wn * 64 + j * 16 + lr][lg * 8];
        #pragma unroll
        for (int i = 0; i < 4; ++i)
            #pragma unroll
            for (int j = 0; j < 4; ++j)
                acc[i][j] = __builtin_amdgcn_mfma_f32_16x16x32_bf16(af[i], bf[j], acc[i][j], 0, 0, 0);
        __syncthreads();
    }

    const int z = (n0 >> 10);
    #pragma unroll
    for (int i = 0; i < 4; ++i) {
        const int mbase = m0 + wm * 64 + i * 16 + lg * 4;
        #pragma unroll
        for (int j = 0; j < 4; ++j) {
            const int n = n0 + wn * 64 + j * 16 + lr;
            const int nn = n & 1023, hh = nn >> 6, hd = nn & 63;
            #pragma unroll
            for (int r = 0; r < 4; ++r) {
                const int mm = mbase + r, bb = mm >> 11, ss = mm & (S - 1);
                const unsigned short val = f2bf(acc[i][j][r]);
                if (z == 0)      q[((size_t)(bb * H + hh) * S + ss) * Hd + hd] = val;
                else if (z == 1) k[((size_t)(bb * H + hh) * S + ss) * Hd + hd] = val;
                else             vt[((size_t)(bb * H + hh) * Hd + hd) * S + ss] = val;
            }
        }
    }
}

// ---------------------------------------------------------------------------
// Output projection MFMA GEMM — unchanged from round 5 (passing).
// ---------------------------------------------------------------------------
__global__ __launch_bounds__(256) void out_mfma_kernel(
    const unsigned short* __restrict__ a, const unsigned short* __restrict__ bt,
    const float* __restrict__ bias, float* __restrict__ out)
{
    __shared__ unsigned short A_lds[128][32];
    __shared__ unsigned short B_lds[128][32];
    const int t = threadIdx.x, w = t >> 6, l = t & 63;
    const int lr = l & 15, lg = l >> 4;
    const int wm = w >> 1, wn = w & 1;
    const int m0 = blockIdx.x * 128, n0 = blockIdx.y * 128;
    const int srow = l >> 2, skofs = (l & 3) * 8;

    f32x4 acc[4][4];
    #pragma unroll
    for (int i = 0; i < 4; ++i)
        #pragma unroll
        for (int j = 0; j < 4; ++j) acc[i][j] = (f32x4){0.f, 0.f, 0.f, 0.f};

    for (int k0 = 0; k0 < K; k0 += 32) {
        #pragma unroll
        for (int p = 0; p < 2; ++p) {
            const int c = w * 2 + p;
            gload_lds16(a  + (size_t)(m0 + c * 16 + srow) * K + k0 + skofs, &A_lds[c * 16][0]);
            gload_lds16(bt + (size_t)(n0 + c * 16 + srow) * K + k0 + skofs, &B_lds[c * 16][0]);
        }
        __syncthreads();
        short8 af[4], bf[4];
        #pragma unroll
        for (int i = 0; i < 4; ++i) af[i] = *(const short8*)&A_lds[wm * 64 + i * 16 + lr][lg * 8];
        #pragma unroll
        for (int j = 0; j < 4; ++j) bf[j] = *(const short8*)&B_lds[wn * 64 + j * 16 + lr][lg * 8];
        #pragma unroll
        for (int i = 0; i < 4; ++i)
            #pragma unroll
            for (int j = 0; j < 4; ++j)
                acc[i][j] = __builtin_amdgcn_mfma_f32_16x16x32_bf16(af[i], bf[j], acc[i][j], 0, 0, 0);
        __syncthreads();
    }

    #pragma unroll
    for (int i = 0; i < 4; ++i) {
        const int mbase = m0 + wm * 64 + i * 16 + lg * 4;
        #pragma unroll
        for (int j = 0; j < 4; ++j) {
            const int n = n0 + wn * 64 + j * 16 + lr;
            const float bv = bias[n];
            #pragma unroll
            for (int r = 0; r < 4; ++r)
                out[(size_t)(mbase + r) * D + n] = acc[i][j][r] + bv;
        }
    }
}

// ---------------------------------------------------------------------------
// MFMA causal flash attention, v2:
//  - block handles q-tile pair (31-x, x): uniform 33 kt-tiles/block
//  - K/V tiles staged in LDS via global_load_lds, double-buffered,
//    counted vmcnt(4) + raw s_barrier (prefetch stays in flight)
//  - XOR-swizzled LDS (T2): linear LDS dest, inverse-swizzled global source,
//    swizzled ds_read (rule #21)
// ---------------------------------------------------------------------------
__device__ __forceinline__ void stage64(const unsigned short* __restrict__ g0,
                                        size_t gstride, unsigned short* lbuf,
                                        int w, int l) {
    // one 64x64 bf16 tile (8 KB); wave w stages chunks w*2, w*2+1 (1 KB each)
    #pragma unroll
    for (int it = 0; it < 2; ++it) {
        const int chunk = w * 2 + it;              // 0..7 -> rows chunk*8..+7
        const int row = chunk * 8 + (l >> 3);
        const int scol = ((l & 7) ^ (row & 7)) * 8;   // inverse-swizzled source
        gload_lds16(g0 + (size_t)row * gstride + scol, lbuf + chunk * 512);
    }
}

__global__ __launch_bounds__(256) void attn_mfma_kernel(
    const unsigned short* __restrict__ q, const unsigned short* __restrict__ k,
    const unsigned short* __restrict__ vt, unsigned short* __restrict__ ctx)
{
    __shared__ unsigned short Kb[2][64 * 64];
    __shared__ unsigned short Vb[2][64 * 64];
    __shared__ unsigned short P_lds[4][16][72];
    const int t = threadIdx.x, w = t >> 6, l = t & 63;
    const int lr = l & 15, lg = l >> 4;
    const int hh = blockIdx.y, bb = blockIdx.z;
    const size_t base  = (size_t)(bb * H + hh) * S * Hd;
    const size_t vbase = (size_t)(bb * H + hh) * Hd * S;

    #pragma unroll 1
    for (int ph = 0; ph < 2; ++ph) {
        const int qt = ph ? (int)blockIdx.x : 31 - (int)blockIdx.x;
        const int q0 = qt * 64 + w * 16;
        const int diag = qt;

        short8 qf[2];
        #pragma unroll
        for (int c = 0; c < 2; ++c)
            qf[c] = *(const short8*)(q + base + (size_t)(q0 + lr) * Hd + c * 32 + lg * 8);

        f32x4 accO[4];
        #pragma unroll
        for (int hb = 0; hb < 4; ++hb) accO[hb] = (f32x4){0.f, 0.f, 0.f, 0.f};
        float mrow[4], lrow[4];
        #pragma unroll
        for (int r = 0; r < 4; ++r) { mrow[r] = -INFINITY; lrow[r] = 0.f; }

        // prologue: stage tile 0 into buffer 0
        stage64(k + base, Hd, Kb[0], w, l);
        stage64(vt + vbase, S, Vb[0], w, l);
        int cur = 0;

        for (int kt = 0; kt <= diag; ++kt) {
            if (kt < diag) {   // prefetch next tile into other buffer
                stage64(k + base + (size_t)(kt + 1) * 64 * Hd, Hd, Kb[cur ^ 1], w, l);
                stage64(vt + vbase + (size_t)(kt + 1) * 64, S, Vb[cur ^ 1], w, l);
                asm volatile("s_waitcnt vmcnt(4)" ::: "memory");
            } else {
                asm volatile("s_waitcnt vmcnt(0)" ::: "memory");
            }
            __builtin_amdgcn_s_barrier();
            asm volatile("" ::: "memory");

            const unsigned short* Kc = Kb[cur];
            const unsigned short* Vc = Vb[cur];

            // ---- S = Q K^T ----
            f32x4 accS[4];
            #pragma unroll
            for (int kc = 0; kc < 4; ++kc) {
                accS[kc] = (f32x4){0.f, 0.f, 0.f, 0.f};
                const int krow = kc * 16 + lr;
                #pragma unroll
                for (int c = 0; c < 2; ++c) {
                    short8 kf = *(const short8*)&Kc[krow * 64 +
                        ((c * 32 + lg * 8) ^ ((krow & 7) * 8))];
                    accS[kc] = __builtin_amdgcn_mfma_f32_16x16x32_bf16(qf[c], kf, accS[kc], 0, 0, 0);
                }
            }

            // ---- online softmax on the 16x64 strip ----
            float ps[4][4];
            #pragma unroll
            for (int kc = 0; kc < 4; ++kc)
                #pragma unroll
                for (int r = 0; r < 4; ++r) {
                    float s = accS[kc][r] * 0.125f;
                    if (kt == diag) {
                        int kj = kt * 64 + kc * 16 + lr;
                        int qi = q0 + lg * 4 + r;
                        if (kj > qi) s = -INFINITY;
                    }
                    ps[kc][r] = s;
                }
            float sf[4];
            #pragma unroll
            for (int r = 0; r < 4; ++r) {
                float tm = fmaxf(fmaxf(ps[0][r], ps[1][r]), fmaxf(ps[2][r], ps[3][r]));
                #pragma unroll
                for (int msk = 1; msk < 16; msk <<= 1)
                    tm = fmaxf(tm, __shfl_xor(tm, msk));
                float mn = fmaxf(mrow[r], tm);
                float rs = 0.f;
                #pragma unroll
                for (int kc = 0; kc < 4; ++kc) {
                    float p = __expf(ps[kc][r] - mn);
                    ps[kc][r] = p;
                    rs += p;
                }
                #pragma unroll
                for (int msk = 1; msk < 16; msk <<= 1)
                    rs += __shfl_xor(rs, msk);
                sf[r] = __expf(mrow[r] - mn);
                lrow[r] = lrow[r] * sf[r] + rs;
                mrow[r] = mn;
            }
            #pragma unroll
            for (int hb = 0; hb < 4; ++hb)
                #pragma unroll
                for (int r = 0; r < 4; ++r) accO[hb][r] *= sf[r];

            // ---- P strip -> per-wave LDS, re-read as A-frags ----
            #pragma unroll
            for (int kc = 0; kc < 4; ++kc)
                #pragma unroll
                for (int r = 0; r < 4; ++r)
                    P_lds[w][lg * 4 + r][kc * 16 + lr] = f2bf(ps[kc][r]);
            short8 pa[2];
            #pragma unroll
            for (int c = 0; c < 2; ++c)
                pa[c] = *(const short8*)&P_lds[w][lr][c * 32 + lg * 8];

            // ---- O += P V ----
            #pragma unroll
            for (int hb = 0; hb < 4; ++hb) {
                const int vrow = hb * 16 + lr;
                #pragma unroll
                for (int c = 0; c < 2; ++c) {
                    short8 vf = *(const short8*)&Vc[vrow * 64 +
                        ((c * 32 + lg * 8) ^ ((vrow & 7) * 8))];
                    accO[hb] = __builtin_amdgcn_mfma_f32_16x16x32_bf16(pa[c], vf, accO[hb], 0, 0, 0);
                }
            }

            asm volatile("" ::: "memory");
            __builtin_amdgcn_s_barrier();
            cur ^= 1;
        }

        // ---- epilogue: ctx[B,S,D] bf16 ----
        #pragma unroll
        for (int r = 0; r < 4; ++r) {
            float inv = 1.f / lrow[r];
            size_t row = (size_t)(bb * S + q0 + lg * 4 + r) * D + hh * Hd;
            #pragma unroll
            for (int hb = 0; hb < 4; ++hb)
                ctx[row + hb * 16 + lr] = f2bf(accO[hb][r] * inv);
        }
    }
}

extern "C" void kernel_launch(void* const* d_in, const int* in_sizes, int n_in,
                              void* d_out, int out_size, void* d_ws, size_t ws_size,
                              hipStream_t stream) {
    const float* x  = (const float*)d_in[0];
    const float* wq = (const float*)d_in[1];
    const float* wk = (const float*)d_in[2];
    const float* wv = (const float*)d_in[3];
    const float* wo = (const float*)d_in[4];
    const float* bo = (const float*)d_in[5];
    float* out = (float*)d_out;

    char* ws = (char*)d_ws;
    unsigned short* x_bf   = (unsigned short*)ws;
    unsigned short* q      = (unsigned short*)(ws + ((size_t)8  << 20));
    unsigned short* kk     = (unsigned short*)(ws + ((size_t)16 << 20));
    unsigned short* vt     = (unsigned short*)(ws + ((size_t)24 << 20));
    unsigned short* ctx    = x_bf;
    unsigned short* wqkv_t = (unsigned short*)(ws + ((size_t)32 << 20));
    unsigned short* wo_t   = (unsigned short*)(ws + ((size_t)38 << 20));

    convert_x_kernel<<<(M * K) / (256 * 8), 256, 0, stream>>>(x, x_bf);
    dim3 gtr(K / 64, K / 64, 4);
    transpose_w_kernel<<<gtr, 256, 0, stream>>>(wq, wk, wv, wo, wqkv_t, wo_t);

    dim3 gqkv(M / 128, 3072 / 128);
    qkv_mfma_kernel<<<gqkv, 256, 0, stream>>>(x_bf, wqkv_t, q, kk, vt);

    dim3 gattn(S / 128, H, B);   // 16 q-tile pairs
    attn_mfma_kernel<<<gattn, 256, 0, stream>>>(q, kk, vt, ctx);

    dim3 gout(M / 128, D / 128);
    out_mfma_kernel<<<gout, 256, 0, stream>>>(ctx, wo_t, bo, out);
}

// Round 7
// 129.225 us; speedup vs baseline: 42.0935x; 1.1241x over previous
//
#include <hip/hip_runtime.h>
#include <hip/hip_bf16.h>

constexpr int B = 2, S = 2048, D = 1024, H = 16, Hd = 64;
constexpr int M = B * S;   // 4096 rows
constexpr int K = 1024;

typedef __attribute__((ext_vector_type(8))) short short8;
typedef __attribute__((ext_vector_type(4))) float f32x4;

__device__ __forceinline__ float bf2f(unsigned short u) {
    return __uint_as_float(((unsigned)u) << 16);
}
__device__ __forceinline__ unsigned short f2bf(float f) {   // RNE
    unsigned u = __float_as_uint(f);
    u += 0x7FFF + ((u >> 16) & 1);
    return (unsigned short)(u >> 16);
}
__device__ __forceinline__ void gload_lds16(const unsigned short* g, unsigned short* l) {
    __builtin_amdgcn_global_load_lds(
        (const __attribute__((address_space(1))) void*)g,
        (__attribute__((address_space(3))) void*)l, 16, 0, 0);
}

// ---------------------------------------------------------------------------
// x fp32 -> bf16, 8 elems/thread
// ---------------------------------------------------------------------------
__global__ __launch_bounds__(256) void convert_x_kernel(
    const float* __restrict__ x, unsigned short* __restrict__ xb)
{
    const size_t i = ((size_t)blockIdx.x * 256 + threadIdx.x) * 8;
    float4 a = *(const float4*)(x + i), b = *(const float4*)(x + i + 4);
    ushort4 u0 = {f2bf(a.x), f2bf(a.y), f2bf(a.z), f2bf(a.w)};
    ushort4 u1 = {f2bf(b.x), f2bf(b.y), f2bf(b.z), f2bf(b.w)};
    *(ushort4*)(xb + i) = u0;
    *(ushort4*)(xb + i + 4) = u1;
}

// ---------------------------------------------------------------------------
// Weight transpose+convert: w [K,N] fp32 -> wt [N,K] bf16 (padded-LDS tile).
// ---------------------------------------------------------------------------
__global__ __launch_bounds__(256) void transpose_w_kernel(
    const float* __restrict__ wq, const float* __restrict__ wk,
    const float* __restrict__ wv, const float* __restrict__ wo,
    unsigned short* __restrict__ wqkv_t, unsigned short* __restrict__ wo_t)
{
    __shared__ float tile[64][65];
    const int z = blockIdx.z;
    const float* w = (z == 0) ? wq : (z == 1) ? wk : (z == 2) ? wv : wo;
    unsigned short* dst = (z == 3) ? wo_t : wqkv_t + (size_t)z * K * K;
    const int k0 = blockIdx.x * 64, n0 = blockIdx.y * 64;
    const int t = threadIdx.x;
    #pragma unroll
    for (int it = 0; it < 16; ++it) {
        int idx = t + it * 256;
        tile[idx >> 6][idx & 63] = w[(size_t)(k0 + (idx >> 6)) * K + n0 + (idx & 63)];
    }
    __syncthreads();
    #pragma unroll
    for (int it = 0; it < 16; ++it) {
        int idx = t + it * 256;
        int r = idx >> 6, c = idx & 63;
        dst[(size_t)(n0 + r) * K + k0 + c] = f2bf(tile[c][r]);
    }
}

// ---------------------------------------------------------------------------
// Fused QKV MFMA GEMM (m97 structure). Q written PRE-SCALED by 0.125.
// ---------------------------------------------------------------------------
__global__ __launch_bounds__(256) void qkv_mfma_kernel(
    const unsigned short* __restrict__ xa, const unsigned short* __restrict__ bt,
    unsigned short* __restrict__ q, unsigned short* __restrict__ k,
    unsigned short* __restrict__ vt)
{
    __shared__ unsigned short A_lds[128][32];
    __shared__ unsigned short B_lds[128][32];
    const int t = threadIdx.x, w = t >> 6, l = t & 63;
    const int lr = l & 15, lg = l >> 4;
    const int wm = w >> 1, wn = w & 1;
    const int m0 = blockIdx.x * 128, n0 = blockIdx.y * 128;
    const int srow = l >> 2, skofs = (l & 3) * 8;

    f32x4 acc[4][4];
    #pragma unroll
    for (int i = 0; i < 4; ++i)
        #pragma unroll
        for (int j = 0; j < 4; ++j) acc[i][j] = (f32x4){0.f, 0.f, 0.f, 0.f};

    for (int k0 = 0; k0 < K; k0 += 32) {
        #pragma unroll
        for (int p = 0; p < 2; ++p) {
            const int c = w * 2 + p;
            gload_lds16(xa + (size_t)(m0 + c * 16 + srow) * K + k0 + skofs, &A_lds[c * 16][0]);
            gload_lds16(bt + (size_t)(n0 + c * 16 + srow) * K + k0 + skofs, &B_lds[c * 16][0]);
        }
        __syncthreads();
        short8 af[4], bf[4];
        #pragma unroll
        for (int i = 0; i < 4; ++i) af[i] = *(const short8*)&A_lds[wm * 64 + i * 16 + lr][lg * 8];
        #pragma unroll
        for (int j = 0; j < 4; ++j) bf[j] = *(const short8*)&B_lds[wn * 64 + j * 16 + lr][lg * 8];
        #pragma unroll
        for (int i = 0; i < 4; ++i)
            #pragma unroll
            for (int j = 0; j < 4; ++j)
                acc[i][j] = __builtin_amdgcn_mfma_f32_16x16x32_bf16(af[i], bf[j], acc[i][j], 0, 0, 0);
        __syncthreads();
    }

    const int z = (n0 >> 10);
    const float scale = (z == 0) ? 0.125f : 1.0f;   // fold 1/sqrt(Hd) into Q
    #pragma unroll
    for (int i = 0; i < 4; ++i) {
        const int mbase = m0 + wm * 64 + i * 16 + lg * 4;
        #pragma unroll
        for (int j = 0; j < 4; ++j) {
            const int n = n0 + wn * 64 + j * 16 + lr;
            const int nn = n & 1023, hh = nn >> 6, hd = nn & 63;
            #pragma unroll
            for (int r = 0; r < 4; ++r) {
                const int mm = mbase + r, bb = mm >> 11, ss = mm & (S - 1);
                const unsigned short val = f2bf(acc[i][j][r] * scale);
                if (z == 0)      q[((size_t)(bb * H + hh) * S + ss) * Hd + hd] = val;
                else if (z == 1) k[((size_t)(bb * H + hh) * S + ss) * Hd + hd] = val;
                else             vt[((size_t)(bb * H + hh) * Hd + hd) * S + ss] = val;
            }
        }
    }
}

// ---------------------------------------------------------------------------
// Output projection MFMA GEMM — unchanged (passing).
// ---------------------------------------------------------------------------
__global__ __launch_bounds__(256) void out_mfma_kernel(
    const unsigned short* __restrict__ a, const unsigned short* __restrict__ bt,
    const float* __restrict__ bias, float* __restrict__ out)
{
    __shared__ unsigned short A_lds[128][32];
    __shared__ unsigned short B_lds[128][32];
    const int t = threadIdx.x, w = t >> 6, l = t & 63;
    const int lr = l & 15, lg = l >> 4;
    const int wm = w >> 1, wn = w & 1;
    const int m0 = blockIdx.x * 128, n0 = blockIdx.y * 128;
    const int srow = l >> 2, skofs = (l & 3) * 8;

    f32x4 acc[4][4];
    #pragma unroll
    for (int i = 0; i < 4; ++i)
        #pragma unroll
        for (int j = 0; j < 4; ++j) acc[i][j] = (f32x4){0.f, 0.f, 0.f, 0.f};

    for (int k0 = 0; k0 < K; k0 += 32) {
        #pragma unroll
        for (int p = 0; p < 2; ++p) {
            const int c = w * 2 + p;
            gload_lds16(a  + (size_t)(m0 + c * 16 + srow) * K + k0 + skofs, &A_lds[c * 16][0]);
            gload_lds16(bt + (size_t)(n0 + c * 16 + srow) * K + k0 + skofs, &B_lds[c * 16][0]);
        }
        __syncthreads();
        short8 af[4], bf[4];
        #pragma unroll
        for (int i = 0; i < 4; ++i) af[i] = *(const short8*)&A_lds[wm * 64 + i * 16 + lr][lg * 8];
        #pragma unroll
        for (int j = 0; j < 4; ++j) bf[j] = *(const short8*)&B_lds[wn * 64 + j * 16 + lr][lg * 8];
        #pragma unroll
        for (int i = 0; i < 4; ++i)
            #pragma unroll
            for (int j = 0; j < 4; ++j)
                acc[i][j] = __builtin_amdgcn_mfma_f32_16x16x32_bf16(af[i], bf[j], acc[i][j], 0, 0, 0);
        __syncthreads();
    }

    #pragma unroll
    for (int i = 0; i < 4; ++i) {
        const int mbase = m0 + wm * 64 + i * 16 + lg * 4;
        #pragma unroll
        for (int j = 0; j < 4; ++j) {
            const int n = n0 + wn * 64 + j * 16 + lr;
            const float bv = bias[n];
            #pragma unroll
            for (int r = 0; r < 4; ++r)
                out[(size_t)(mbase + r) * D + n] = acc[i][j][r] + bv;
        }
    }
}

// ---------------------------------------------------------------------------
// MFMA causal flash attention, v3:
//  - SWAPPED QK^T (mfma(K,Q) -> S^T): lane owns 16 scores of ONE q-column;
//    softmax reduce = 2 shfl_xor (masks 16,32); m,l are scalars.
//  - un-paired q-tiles, qt rotated per (h,b) for CU load balance; grid 1024
//    blocks = 4 blocks/CU; LDS 33 KB -> 16 waves/CU cap.
//  - K double-buffered (counted vmcnt), V single-buffered (issued at iter
//    top, latency hidden under QK+softmax).
// ---------------------------------------------------------------------------
__device__ __forceinline__ void stage64(const unsigned short* __restrict__ g0,
                                        size_t gstride, unsigned short* lbuf,
                                        int w, int l) {
    #pragma unroll
    for (int it = 0; it < 2; ++it) {
        const int chunk = w * 2 + it;
        const int row = chunk * 8 + (l >> 3);
        const int scol = ((l & 7) ^ (row & 7)) * 8;   // inverse-swizzled source
        gload_lds16(g0 + (size_t)row * gstride + scol, lbuf + chunk * 512);
    }
}

__global__ __launch_bounds__(256) void attn_mfma_kernel(
    const unsigned short* __restrict__ q, const unsigned short* __restrict__ k,
    const unsigned short* __restrict__ vt, unsigned short* __restrict__ ctx)
{
    __shared__ unsigned short Kb[2][64 * 64];
    __shared__ unsigned short Vb[64 * 64];
    __shared__ unsigned short P_lds[4][16][72];
    const int t = threadIdx.x, w = t >> 6, l = t & 63;
    const int lr = l & 15, lg = l >> 4;
    const int hh = blockIdx.y, bb = blockIdx.z;
    const int qt = (blockIdx.x + 5 * blockIdx.y + 16 * blockIdx.z) & 31;
    const int q0 = qt * 64 + w * 16;
    const int diag = qt;
    const size_t base  = (size_t)(bb * H + hh) * S * Hd;
    const size_t vbase = (size_t)(bb * H + hh) * Hd * S;

    short8 qf[2];
    #pragma unroll
    for (int c = 0; c < 2; ++c)
        qf[c] = *(const short8*)(q + base + (size_t)(q0 + lr) * Hd + c * 32 + lg * 8);

    f32x4 accO[4];
    #pragma unroll
    for (int hb = 0; hb < 4; ++hb) accO[hb] = (f32x4){0.f, 0.f, 0.f, 0.f};
    float m_run = -INFINITY, l_run = 0.f;

    stage64(k + base, Hd, Kb[0], w, l);
    int cur = 0;

    for (int kt = 0; kt <= diag; ++kt) {
        stage64(vt + vbase + (size_t)kt * 64, S, Vb, w, l);
        if (kt < diag) {
            stage64(k + base + (size_t)(kt + 1) * 64 * Hd, Hd, Kb[cur ^ 1], w, l);
            asm volatile("s_waitcnt vmcnt(4)" ::: "memory");   // K[kt] arrived
        } else {
            asm volatile("s_waitcnt vmcnt(2)" ::: "memory");   // K[kt] arrived
        }
        __builtin_amdgcn_sched_barrier(0);
        __builtin_amdgcn_s_barrier();

        const unsigned short* Kc = Kb[cur];

        // ---- S^T = K Q^T (swapped): lane = (k-subrow lg*4+r, q-col lr) ----
        f32x4 accS[4];
        #pragma unroll
        for (int kc = 0; kc < 4; ++kc) {
            accS[kc] = (f32x4){0.f, 0.f, 0.f, 0.f};
            const int krow = kc * 16 + lr;
            #pragma unroll
            for (int c = 0; c < 2; ++c) {
                short8 kf = *(const short8*)&Kc[krow * 64 +
                    ((c * 32 + lg * 8) ^ ((krow & 7) * 8))];
                accS[kc] = __builtin_amdgcn_mfma_f32_16x16x32_bf16(kf, qf[c], accS[kc], 0, 0, 0);
            }
        }

        // ---- online softmax: lane owns column q = lr (16 of 64 k-vals) ----
        float ps[4][4];
        #pragma unroll
        for (int kc = 0; kc < 4; ++kc)
            #pragma unroll
            for (int r = 0; r < 4; ++r) {
                float s = accS[kc][r];
                if (kt == diag) {
                    if (kc * 16 + lg * 4 + r > w * 16 + lr) s = -INFINITY;
                }
                ps[kc][r] = s;
            }
        float mloc = -INFINITY;
        #pragma unroll
        for (int kc = 0; kc < 4; ++kc)
            #pragma unroll
            for (int r = 0; r < 4; ++r) mloc = fmaxf(mloc, ps[kc][r]);
        mloc = fmaxf(mloc, __shfl_xor(mloc, 16));
        mloc = fmaxf(mloc, __shfl_xor(mloc, 32));
        const float mn = fmaxf(m_run, mloc);
        float rs = 0.f;
        #pragma unroll
        for (int kc = 0; kc < 4; ++kc)
            #pragma unroll
            for (int r = 0; r < 4; ++r) {
                float p = __expf(ps[kc][r] - mn);
                ps[kc][r] = p;
                rs += p;
            }
        rs += __shfl_xor(rs, 16);
        rs += __shfl_xor(rs, 32);
        const float sfc = __expf(m_run - mn);
        l_run = l_run * sfc + rs;
        m_run = mn;
        float sfq[4];
        #pragma unroll
        for (int r = 0; r < 4; ++r) sfq[r] = __shfl(sfc, lg * 4 + r);
        #pragma unroll
        for (int hb = 0; hb < 4; ++hb)
            #pragma unroll
            for (int r = 0; r < 4; ++r) accO[hb][r] *= sfq[r];

        // ---- P^T in regs -> P_lds[q][k] (paired b32 writes), read A-frags --
        #pragma unroll
        for (int kc = 0; kc < 4; ++kc)
            #pragma unroll
            for (int rp = 0; rp < 2; ++rp)
                *(__hip_bfloat162*)&P_lds[w][lr][kc * 16 + lg * 4 + rp * 2] =
                    __float22bfloat162_rn(make_float2(ps[kc][rp * 2], ps[kc][rp * 2 + 1]));
        short8 pa[2];
        #pragma unroll
        for (int c = 0; c < 2; ++c)
            pa[c] = *(const short8*)&P_lds[w][lr][c * 32 + lg * 8];

        // ---- wait V[kt], then O += P V ----
        if (kt < diag) asm volatile("s_waitcnt vmcnt(2)" ::: "memory");
        else           asm volatile("s_waitcnt vmcnt(0)" ::: "memory");
        __builtin_amdgcn_sched_barrier(0);
        __builtin_amdgcn_s_barrier();

        #pragma unroll
        for (int hb = 0; hb < 4; ++hb) {
            const int vrow = hb * 16 + lr;
            #pragma unroll
            for (int c = 0; c < 2; ++c) {
                short8 vf = *(const short8*)&Vb[vrow * 64 +
                    ((c * 32 + lg * 8) ^ ((vrow & 7) * 8))];
                accO[hb] = __builtin_amdgcn_mfma_f32_16x16x32_bf16(pa[c], vf, accO[hb], 0, 0, 0);
            }
        }

        __builtin_amdgcn_sched_barrier(0);
        __builtin_amdgcn_s_barrier();   // Vb / Kb[cur] reusable
        cur ^= 1;
    }

    // ---- epilogue ----
    const float inv = 1.f / l_run;
    float invq[4];
    #pragma unroll
    for (int r = 0; r < 4; ++r) invq[r] = __shfl(inv, lg * 4 + r);
    #pragma unroll
    for (int r = 0; r < 4; ++r) {
        size_t row = (size_t)(bb * S + q0 + lg * 4 + r) * D + hh * Hd;
        #pragma unroll
        for (int hb = 0; hb < 4; ++hb)
            ctx[row + hb * 16 + lr] = f2bf(accO[hb][r] * invq[r]);
    }
}

extern "C" void kernel_launch(void* const* d_in, const int* in_sizes, int n_in,
                              void* d_out, int out_size, void* d_ws, size_t ws_size,
                              hipStream_t stream) {
    const float* x  = (const float*)d_in[0];
    const float* wq = (const float*)d_in[1];
    const float* wk = (const float*)d_in[2];
    const float* wv = (const float*)d_in[3];
    const float* wo = (const float*)d_in[4];
    const float* bo = (const float*)d_in[5];
    float* out = (float*)d_out;

    char* ws = (char*)d_ws;
    unsigned short* x_bf   = (unsigned short*)ws;
    unsigned short* q      = (unsigned short*)(ws + ((size_t)8  << 20));
    unsigned short* kk     = (unsigned short*)(ws + ((size_t)16 << 20));
    unsigned short* vt     = (unsigned short*)(ws + ((size_t)24 << 20));
    unsigned short* ctx    = x_bf;
    unsigned short* wqkv_t = (unsigned short*)(ws + ((size_t)32 << 20));
    unsigned short* wo_t   = (unsigned short*)(ws + ((size_t)38 << 20));

    convert_x_kernel<<<(M * K) / (256 * 8), 256, 0, stream>>>(x, x_bf);
    dim3 gtr(K / 64, K / 64, 4);
    transpose_w_kernel<<<gtr, 256, 0, stream>>>(wq, wk, wv, wo, wqkv_t, wo_t);

    dim3 gqkv(M / 128, 3072 / 128);
    qkv_mfma_kernel<<<gqkv, 256, 0, stream>>>(x_bf, wqkv_t, q, kk, vt);

    dim3 gattn(S / 64, H, B);   // un-paired, qt rotated per (h,b)
    attn_mfma_kernel<<<gattn, 256, 0, stream>>>(q, kk, vt, ctx);

    dim3 gout(M / 128, D / 128);
    out_mfma_kernel<<<gout, 256, 0, stream>>>(ctx, wo_t, bo, out);
}